// Round 6
// baseline (50.716 us; speedup 1.0000x reference)
//
#include <hip/hip_runtime.h>

#define N_Q   50000
#define N_S   50000
#define M_NB  32
#define K_PTS 15
#define CIN   64
#define COUT  64
#define NPAIRS  (N_Q * M_NB)
#define NQUADS  (NPAIRS / 4)          // one thread handles 4 neighbors
#define NBUCK 256
#define GEMV_BLOCKS_PER_BUCKET 8

// ws layout:
//   [0, 1024)             : int counters[NBUCK]
//   [1024, 1024 + N_S*16) : float4 s4[N_S]
//   [EV_OFF, ...)         : int4 events[NBUCK][cap]
#define CTR_BYTES 1024
#define S4_BYTES  (N_S * 16)
#define EV_OFF    (CTR_BYTES + S4_BYTES)

// ---------- kernel A: zero out + zero counters + support [N0,3]->float4 ----------
__global__ __launch_bounds__(256) void prep_kernel(
    const float* __restrict__ support,
    float4*      __restrict__ s4,
    int*         __restrict__ counters,
    float4*      __restrict__ out4)     // N_Q*COUT/4 float4s
{
    const int t  = blockIdx.x * 256 + threadIdx.x;
    const int nt = gridDim.x * 256;

    if (t < NBUCK) counters[t] = 0;

    for (int i = t; i < N_S; i += nt)
        s4[i] = make_float4(support[i * 3 + 0], support[i * 3 + 1],
                            support[i * 3 + 2], 0.f);

    const int nout4 = N_Q * COUT / 4;
    const float4 z = make_float4(0.f, 0.f, 0.f, 0.f);
    for (int i = t; i < nout4; i += nt)
        out4[i] = z;
}

// ---------- kernel B: one thread per 4 (n,m) pairs; 4-way MLP on gathers ----------
// w[k][m] > 0 requires ||nb - kp|| < 0.05 with ||kp|| <= 0.0495
//   => ||nb||^2 < 0.009901  (use 0.0101 conservative)
__global__ __launch_bounds__(256) void pair_kernel(
    const float*  __restrict__ query,     // [N,3]
    const float4* __restrict__ s4,        // [N0]
    const int4*   __restrict__ neighbors4,// [N*M/4] (4 neighbor idx per load)
    const float*  __restrict__ kpts,      // [K,3]
    int*          __restrict__ counters,  // [NBUCK]
    int4*         __restrict__ events,    // [NBUCK][cap]
    int cap)
{
    __shared__ float s_kx[K_PTS], s_ky[K_PTS], s_kz[K_PTS], s_kk[K_PTS];
    if (threadIdx.x < K_PTS) {
        float kx = kpts[threadIdx.x * 3 + 0];
        float ky = kpts[threadIdx.x * 3 + 1];
        float kz = kpts[threadIdx.x * 3 + 2];
        s_kx[threadIdx.x] = kx; s_ky[threadIdx.x] = ky; s_kz[threadIdx.x] = kz;
        s_kk[threadIdx.x] = kx * kx + ky * ky + kz * kz;
    }
    __syncthreads();

    const int t = blockIdx.x * 256 + threadIdx.x;   // t in [0, NQUADS)
    if (t >= NQUADS) return;
    const int n = t >> 3;                           // 8 quads per query point

    const int4 nb = neighbors4[t];                  // coalesced 16B

    // Issue all (up to 4) gathers before any use -> overlapped latency.
    float4 p0, p1, p2, p3;
    const bool v0 = nb.x < N_S, v1 = nb.y < N_S, v2 = nb.z < N_S, v3 = nb.w < N_S;
    p0 = v0 ? s4[nb.x] : make_float4(1e6f, 1e6f, 1e6f, 0.f);
    p1 = v1 ? s4[nb.y] : make_float4(1e6f, 1e6f, 1e6f, 0.f);
    p2 = v2 ? s4[nb.z] : make_float4(1e6f, 1e6f, 1e6f, 0.f);
    p3 = v3 ? s4[nb.w] : make_float4(1e6f, 1e6f, 1e6f, 0.f);

    const float qx = query[n * 3 + 0];              // broadcast within 8 threads
    const float qy = query[n * 3 + 1];
    const float qz = query[n * 3 + 2];

    float dx[4], dy[4], dz[4], nn[4];
    dx[0] = p0.x - qx; dy[0] = p0.y - qy; dz[0] = p0.z - qz;
    dx[1] = p1.x - qx; dy[1] = p1.y - qy; dz[1] = p1.z - qz;
    dx[2] = p2.x - qx; dy[2] = p2.y - qy; dz[2] = p2.z - qz;
    dx[3] = p3.x - qx; dy[3] = p3.y - qy; dz[3] = p3.z - qz;
    #pragma unroll
    for (int j = 0; j < 4; ++j)
        nn[j] = dx[j]*dx[j] + dy[j]*dy[j] + dz[j]*dz[j];

    // fast wave-uniform skip: the overwhelmingly common case
    const bool any_close = (nn[0] < 0.0101f) | (nn[1] < 0.0101f) |
                           (nn[2] < 0.0101f) | (nn[3] < 0.0101f);
    if (!__any(any_close)) return;

    const int idxs[4] = { nb.x, nb.y, nb.z, nb.w };
    const int bucket = blockIdx.x & (NBUCK - 1);
    int* ctr  = counters + bucket;
    int4* evb = events + (size_t)bucket * cap;

    #pragma unroll
    for (int j = 0; j < 4; ++j) {
        if (nn[j] >= 0.0101f) continue;
        #pragma unroll
        for (int k = 0; k < K_PTS; ++k) {
            float dot = dx[j]*s_kx[k] + dy[j]*s_ky[k] + dz[j]*s_kz[k];
            float sq  = nn[j] - 2.f * dot + s_kk[k];  // same expansion as reference
            sq = fmaxf(sq, 0.f);
            if (sq < 0.0025f) {                        // sqrt(sq) < 0.05 => w > 0
                float w = 1.f - sqrtf(sq) * 20.f;      // 1/0.05 == 20 exactly
                int slot = atomicAdd(ctr, 1);
                if (slot < cap)
                    evb[slot] = make_int4(n, k, idxs[j], __float_as_int(w));
            }
        }
    }
}

// ---------- kernel C: 8 blocks per bucket; scalar x-loads; 4 accumulators ----------
__global__ __launch_bounds__(256) void gemv_kernel(
    const int*  __restrict__ counters,
    const int4* __restrict__ events,
    int cap,
    const float* __restrict__ x,       // [N0,CIN]
    const float* __restrict__ weight,  // [K,CIN,COUT]
    float*       __restrict__ out)     // [N,COUT]
{
    const int lane = threadIdx.x & 63;
    const int wv   = threadIdx.x >> 6;                       // 0..3
    const int b    = blockIdx.x >> 3;                        // bucket
    const int sub  = blockIdx.x & (GEMV_BLOCKS_PER_BUCKET-1);
    const int cnt  = min(counters[b], cap);
    const int4* evb = events + (size_t)b * cap;

    for (int e = sub * 4 + wv; e < cnt; e += 4 * GEMV_BLOCKS_PER_BUCKET) {
        const int4 ev = evb[e];
        // ev is wave-uniform: hoist to SGPRs so x-row reads become s_loads
        const int   n   = __builtin_amdgcn_readfirstlane(ev.x);
        const int   k   = __builtin_amdgcn_readfirstlane(ev.y);
        const int   idx = __builtin_amdgcn_readfirstlane(ev.z);
        const float w   = __int_as_float(__builtin_amdgcn_readfirstlane(ev.w));

        const float* xr = x + (size_t)idx * CIN;             // uniform -> s_load
        const float* wp = weight + (size_t)k * CIN * COUT + lane;

        float t0 = 0.f, t1 = 0.f, t2 = 0.f, t3 = 0.f;
        #pragma unroll
        for (int c = 0; c < CIN; c += 4) {
            t0 = fmaf(xr[c + 0], wp[(c + 0) * COUT], t0);
            t1 = fmaf(xr[c + 1], wp[(c + 1) * COUT], t1);
            t2 = fmaf(xr[c + 2], wp[(c + 2) * COUT], t2);
            t3 = fmaf(xr[c + 3], wp[(c + 3) * COUT], t3);
        }
        atomicAdd(&out[(size_t)n * COUT + lane], w * ((t0 + t1) + (t2 + t3)));
    }
}

extern "C" void kernel_launch(void* const* d_in, const int* in_sizes, int n_in,
                              void* d_out, int out_size, void* d_ws, size_t ws_size,
                              hipStream_t stream) {
    const float* query     = (const float*)d_in[0];
    const float* support   = (const float*)d_in[1];
    const int*   neighbors = (const int*)  d_in[2];
    const float* x         = (const float*)d_in[3];
    const float* kpts      = (const float*)d_in[4];
    const float* weight    = (const float*)d_in[5];
    float*       out       = (float*)d_out;

    char*   ws       = (char*)d_ws;
    int*    counters = (int*)ws;
    float4* s4       = (float4*)(ws + CTR_BYTES);
    int4*   events   = (int4*)(ws + EV_OFF);
    int     cap      = (int)((ws_size - EV_OFF) / sizeof(int4) / NBUCK);

    prep_kernel<<<2048, 256, 0, stream>>>(support, s4, counters, (float4*)out);
    pair_kernel<<<(NQUADS + 255) / 256, 256, 0, stream>>>(
        query, s4, (const int4*)neighbors, kpts, counters, events, cap);
    gemv_kernel<<<NBUCK * GEMV_BLOCKS_PER_BUCKET, 256, 0, stream>>>(
        counters, events, cap, x, weight, out);
}

// Round 7
// 48.517 us; speedup vs baseline: 1.0453x; 1.0453x over previous
//
#include <hip/hip_runtime.h>

#define N_Q   50000
#define N_S   50000
#define M_NB  32
#define K_PTS 15
#define CIN   64
#define COUT  64
#define NPAIRS      (N_Q * M_NB)          // 1,600,000
#define PAIR_BLOCKS (NPAIRS / 256)        // 6250 (exact)
#define EV_CAP      128                   // per-block event cap (Poisson mean ~1.9)

// ws layout:
//   [0, 32768)                : int counters[PAIR_BLOCKS]  (6250 used)
//   [32768, 32768 + N_S*16)   : float4 s4[N_S]
//   [EV_OFF, ...)             : int4 events[PAIR_BLOCKS][EV_CAP]   (~12.8 MB)
#define CTR_BYTES 32768
#define S4_BYTES  (N_S * 16)
#define EV_OFF    (CTR_BYTES + S4_BYTES)

// ---------- kernel A (tiny): support [N0,3] -> float4 [N0,4] ----------
__global__ __launch_bounds__(256) void prep_s4(
    const float* __restrict__ support, float4* __restrict__ s4)
{
    int i = blockIdx.x * 256 + threadIdx.x;
    if (i < N_S)
        s4[i] = make_float4(support[i * 3 + 0], support[i * 3 + 1],
                            support[i * 3 + 2], 0.f);
}

// ---------- kernel B: 1 pair/thread; LDS event buffer; block-private flush ----
// Also zeroes `out` (grid-stride) — runs entirely before gemv (stream order).
// w[k][m] > 0 requires ||nb - kp|| < 0.05 with ||kp|| <= 0.0495
//   => ||nb||^2 < 0.009901  (use 0.0101 conservative)
__global__ __launch_bounds__(256) void pair_kernel(
    const float*  __restrict__ query,     // [N,3]
    const float4* __restrict__ s4,        // [N0]
    const int*    __restrict__ neighbors, // [N,M] flat
    const float*  __restrict__ kpts,      // [K,3]
    int*          __restrict__ counters,  // [PAIR_BLOCKS]
    int4*         __restrict__ events,    // [PAIR_BLOCKS][EV_CAP]
    float4*       __restrict__ out4)      // N_Q*COUT/4 float4s
{
    __shared__ float s_kx[K_PTS], s_ky[K_PTS], s_kz[K_PTS], s_kk[K_PTS];
    __shared__ int   s_cnt;
    __shared__ int4  s_ev[EV_CAP];

    if (threadIdx.x == 0) s_cnt = 0;
    if (threadIdx.x < K_PTS) {
        float kx = kpts[threadIdx.x * 3 + 0];
        float ky = kpts[threadIdx.x * 3 + 1];
        float kz = kpts[threadIdx.x * 3 + 2];
        s_kx[threadIdx.x] = kx; s_ky[threadIdx.x] = ky; s_kz[threadIdx.x] = kz;
        s_kk[threadIdx.x] = kx * kx + ky * ky + kz * kz;
    }

    const int t  = blockIdx.x * 256 + threadIdx.x;   // t in [0, NPAIRS)
    const int nt = PAIR_BLOCKS * 256;

    // zero the output (independent work; overlaps the gather latency below)
    const float4 z = make_float4(0.f, 0.f, 0.f, 0.f);
    for (int i = t; i < N_Q * COUT / 4; i += nt)
        out4[i] = z;

    __syncthreads();   // s_cnt / kpt tables ready

    const int idx = neighbors[t];                    // coalesced
    if (idx < N_S) {                                 // idx==N_S: shadow, w==0
        float4 p = s4[idx];                          // one dwordx4 gather
        const int n = t >> 5;
        const float dx = p.x - query[n * 3 + 0];
        const float dy = p.y - query[n * 3 + 1];
        const float dz = p.z - query[n * 3 + 2];
        const float nn = dx * dx + dy * dy + dz * dz;
        if (nn < 0.0101f) {
            #pragma unroll
            for (int k = 0; k < K_PTS; ++k) {
                float dot = dx * s_kx[k] + dy * s_ky[k] + dz * s_kz[k];
                float sq  = nn - 2.f * dot + s_kk[k];   // same expansion as ref
                sq = fmaxf(sq, 0.f);
                if (sq < 0.0025f) {                      // sqrt(sq)<0.05 => w>0
                    float w = 1.f - sqrtf(sq) * 20.f;    // 1/0.05 == 20 exactly
                    int slot = atomicAdd(&s_cnt, 1);     // LDS atomic (fast)
                    if (slot < EV_CAP)
                        s_ev[slot] = make_int4(n, k, idx, __float_as_int(w));
                }
            }
        }
    }

    __syncthreads();   // all appends done
    const int cnt = min(s_cnt, EV_CAP);
    if (threadIdx.x == 0) counters[blockIdx.x] = cnt;   // written EVERY call
    if (threadIdx.x < cnt)
        events[(size_t)blockIdx.x * EV_CAP + threadIdx.x] = s_ev[threadIdx.x];
}

// ---------- kernel C: one wave per pair-block bucket; scalar x-loads ----------
__global__ __launch_bounds__(256) void gemv_kernel(
    const int*  __restrict__ counters,
    const int4* __restrict__ events,
    const float* __restrict__ x,       // [N0,CIN]
    const float* __restrict__ weight,  // [K,CIN,COUT]
    float*       __restrict__ out)     // [N,COUT]
{
    const int lane = threadIdx.x & 63;
    const int b    = (blockIdx.x * 256 + threadIdx.x) >> 6;   // wave id = bucket
    if (b >= PAIR_BLOCKS) return;

    const int cnt = counters[b];                     // wave-uniform s_load
    const int4* evb = events + (size_t)b * EV_CAP;

    for (int e = 0; e < cnt; ++e) {
        const int4 ev = evb[e];
        // ev is wave-uniform: hoist to SGPRs so x-row reads become s_loads
        const int   n   = __builtin_amdgcn_readfirstlane(ev.x);
        const int   k   = __builtin_amdgcn_readfirstlane(ev.y);
        const int   idx = __builtin_amdgcn_readfirstlane(ev.z);
        const float w   = __int_as_float(__builtin_amdgcn_readfirstlane(ev.w));

        const float* xr = x + (size_t)idx * CIN;              // uniform -> s_load
        const float* wp = weight + (size_t)k * CIN * COUT + lane;

        float t0 = 0.f, t1 = 0.f, t2 = 0.f, t3 = 0.f;
        #pragma unroll
        for (int c = 0; c < CIN; c += 4) {
            t0 = fmaf(xr[c + 0], wp[(c + 0) * COUT], t0);
            t1 = fmaf(xr[c + 1], wp[(c + 1) * COUT], t1);
            t2 = fmaf(xr[c + 2], wp[(c + 2) * COUT], t2);
            t3 = fmaf(xr[c + 3], wp[(c + 3) * COUT], t3);
        }
        atomicAdd(&out[(size_t)n * COUT + lane], w * ((t0 + t1) + (t2 + t3)));
    }
}

extern "C" void kernel_launch(void* const* d_in, const int* in_sizes, int n_in,
                              void* d_out, int out_size, void* d_ws, size_t ws_size,
                              hipStream_t stream) {
    const float* query     = (const float*)d_in[0];
    const float* support   = (const float*)d_in[1];
    const int*   neighbors = (const int*)  d_in[2];
    const float* x         = (const float*)d_in[3];
    const float* kpts      = (const float*)d_in[4];
    const float* weight    = (const float*)d_in[5];
    float*       out       = (float*)d_out;

    char*   ws       = (char*)d_ws;
    int*    counters = (int*)ws;
    float4* s4       = (float4*)(ws + CTR_BYTES);
    int4*   events   = (int4*)(ws + EV_OFF);

    prep_s4<<<(N_S + 255) / 256, 256, 0, stream>>>(support, s4);
    pair_kernel<<<PAIR_BLOCKS, 256, 0, stream>>>(
        query, s4, neighbors, kpts, counters, events, (float4*)out);
    gemv_kernel<<<(PAIR_BLOCKS * 64 + 255) / 256, 256, 0, stream>>>(
        counters, events, x, weight, out);
}

// Round 8
// 32.523 us; speedup vs baseline: 1.5594x; 1.4918x over previous
//
#include <hip/hip_runtime.h>

#define N_Q   50000
#define N_S   50000
#define M_NB  32
#define K_PTS 15
#define CIN   64
#define COUT  64

// One wave per query point. Fully fused: no workspace, no atomics, no pre-zero.
//
// Sparsity fact (exact, not approximate): w[k][m] = max(1 - d/0.05, 0) with
// ||kp|| <= 0.0495, so w > 0 requires ||nb||^2 < 0.009901 (0.0101 conservative).
// For uniform-random neighbor indices this holds for ~0.4% of pairs, so ~87%
// of waves write a zero row and exit.
//
// Close waves: for each k, every nonzero (k,m) "event" accumulates
//   racc[c=lane] += w * x[idx][c]          (coalesced row load, 1 fma, no shfl)
// then one 64x64 GEMV per active k:
//   tout[o=lane] += sum_c racc[c] * W[k][c][o]   (racc broadcast via LDS)
__global__ __launch_bounds__(256) void kpconv_fused(
    const float* __restrict__ query,     // [N,3]
    const float* __restrict__ support,   // [N0,3]
    const int*   __restrict__ neighbors, // [N,M]
    const float* __restrict__ x,         // [N0,CIN]
    const float* __restrict__ kpts,      // [K,3]
    const float* __restrict__ weight,    // [K,CIN,COUT]
    float*       __restrict__ out)       // [N,COUT]
{
    __shared__ float s_kx[K_PTS], s_ky[K_PTS], s_kz[K_PTS], s_kk[K_PTS];
    __shared__ float s_bc[4][CIN];       // per-wave broadcast buffer

    const int tid = threadIdx.x;
    if (tid < K_PTS) {
        float kx = kpts[tid * 3 + 0];
        float ky = kpts[tid * 3 + 1];
        float kz = kpts[tid * 3 + 2];
        s_kx[tid] = kx; s_ky[tid] = ky; s_kz[tid] = kz;
        s_kk[tid] = kx * kx + ky * ky + kz * kz;   // same 3-term fp32 sum as ref
    }
    __syncthreads();

    const int wv   = tid >> 6;
    const int lane = tid & 63;
    const int n    = blockIdx.x * 4 + wv;          // grid = N_Q/4 exactly

    const int m   = lane & 31;
    const int idx = neighbors[n * M_NB + m];       // coalesced (high half dups)

    float dx = 0.f, dy = 0.f, dz = 0.f, nn = 1e30f;
    if (lane < 32 && idx < N_S) {                  // idx==N_S: shadow, w==0
        const float qx = query[n * 3 + 0];
        const float qy = query[n * 3 + 1];
        const float qz = query[n * 3 + 2];
        dx = support[idx * 3 + 0] - qx;
        dy = support[idx * 3 + 1] - qy;
        dz = support[idx * 3 + 2] - qz;
        nn = dx * dx + dy * dy + dz * dz;
    }

    float tout = 0.f;

    if (__ballot(nn < 0.0101f)) {                  // wave-uniform; ~13% taken
        for (int k = 0; k < K_PTS; ++k) {
            float w = 0.f;
            if (nn < 0.0101f) {
                float dot = dx * s_kx[k] + dy * s_ky[k] + dz * s_kz[k];
                float sq  = fmaxf(nn - 2.f * dot + s_kk[k], 0.f);  // ref expansion
                if (sq < 0.0025f)                   // sqrt(sq) < 0.05 => w > 0
                    w = 1.f - sqrtf(sq) * 20.f;     // 1/0.05 == 20 exactly
            }
            unsigned long long em = __ballot(w > 0.f);
            if (!em) continue;                      // common: this k has no hits

            // accumulate weighted feature row for this k (lane == channel c)
            float racc = 0.f;
            do {
                const int   src  = __ffsll(em) - 1; em &= em - 1;
                const float wsrc = __shfl(w,   src);
                const int   isrc = __shfl(idx, src);
                racc = fmaf(wsrc, x[(size_t)isrc * CIN + lane], racc);
            } while (em);

            // GEMV: tout[o=lane] += sum_c racc[c] * W[k][c][o]
            s_bc[wv][lane] = racc;
            asm volatile("" ::: "memory");          // order ds_write before reads
            const float* wk = weight + (size_t)k * CIN * COUT;
            float p0 = 0.f, p1 = 0.f, p2 = 0.f, p3 = 0.f;
            #pragma unroll 8
            for (int c = 0; c < CIN; c += 4) {
                p0 = fmaf(s_bc[wv][c + 0], wk[(c + 0) * COUT + lane], p0);
                p1 = fmaf(s_bc[wv][c + 1], wk[(c + 1) * COUT + lane], p1);
                p2 = fmaf(s_bc[wv][c + 2], wk[(c + 2) * COUT + lane], p2);
                p3 = fmaf(s_bc[wv][c + 3], wk[(c + 3) * COUT + lane], p3);
            }
            tout += (p0 + p1) + (p2 + p3);
        }
    }

    out[(size_t)n * COUT + lane] = tout;           // each wave owns its row
}

extern "C" void kernel_launch(void* const* d_in, const int* in_sizes, int n_in,
                              void* d_out, int out_size, void* d_ws, size_t ws_size,
                              hipStream_t stream) {
    const float* query     = (const float*)d_in[0];
    const float* support   = (const float*)d_in[1];
    const int*   neighbors = (const int*)  d_in[2];
    const float* x         = (const float*)d_in[3];
    const float* kpts      = (const float*)d_in[4];
    const float* weight    = (const float*)d_in[5];
    float*       out       = (float*)d_out;

    kpconv_fused<<<N_Q / 4, 256, 0, stream>>>(      // 12500 blocks, 4 waves each
        query, support, neighbors, x, kpts, weight, out);
}

// Round 9
// 28.756 us; speedup vs baseline: 1.7637x; 1.1310x over previous
//
#include <hip/hip_runtime.h>

#define N_Q   50000
#define N_S   50000
#define M_NB  32
#define K_PTS 15
#define CIN   64
#define COUT  64

// One wave per TWO query points: lanes 0-31 -> point A's 32 neighbors,
// lanes 32-63 -> point B's. Fully fused, no workspace, no atomics.
//
// Sparsity (exact): w[k][m] = max(1 - d/0.05, 0), ||kp|| <= 0.0495, so w > 0
// requires ||nb||^2 < 0.009901 (0.0101 conservative). ~0.4% of pairs qualify,
// so ~77% of (2-point) waves write two zero rows and exit.
//
// Close path per active k and half H:
//   racc[c=lane] += w * x[idx][c]            (coalesced row, 64-wide)
//   tout_H[o=lane] += sum_c racc[c]*W[k][c][o]  (racc via LDS broadcast)
__global__ __launch_bounds__(128) void kpconv_fused2(
    const float* __restrict__ query,     // [N,3]
    const float* __restrict__ support,   // [N0,3]
    const int*   __restrict__ neighbors, // [N,M]
    const float* __restrict__ x,         // [N0,CIN]
    const float* __restrict__ kpts,      // [K,3]
    const float* __restrict__ weight,    // [K,CIN,COUT]
    float*       __restrict__ out)       // [N,COUT]
{
    __shared__ float s_kx[K_PTS], s_ky[K_PTS], s_kz[K_PTS], s_kk[K_PTS];
    __shared__ float s_bc[2][CIN];       // per-wave broadcast buffer

    const int tid = threadIdx.x;
    if (tid < K_PTS) {
        float kx = kpts[tid * 3 + 0];
        float ky = kpts[tid * 3 + 1];
        float kz = kpts[tid * 3 + 2];
        s_kx[tid] = kx; s_ky[tid] = ky; s_kz[tid] = kz;
        s_kk[tid] = kx * kx + ky * ky + kz * kz;   // same 3-term fp32 sum as ref
    }
    __syncthreads();

    const int wv   = tid >> 6;                    // 0..1
    const int lane = tid & 63;
    const int base = blockIdx.x * 4 + wv * 2;     // grid = N_Q/4 blocks exactly
    const int h    = lane >> 5;                   // half: 0 -> point A, 1 -> B
    const int n    = base + h;                    // this lane's query point
    const int m    = lane & 31;

    const int idx = neighbors[n * M_NB + m];      // coalesced (2 rows/wave)

    float dx = 0.f, dy = 0.f, dz = 0.f, nn = 1e30f;
    if (idx < N_S) {                              // idx==N_S: shadow, w==0
        dx = support[idx * 3 + 0] - query[n * 3 + 0];
        dy = support[idx * 3 + 1] - query[n * 3 + 1];
        dz = support[idx * 3 + 2] - query[n * 3 + 2];
        nn = dx * dx + dy * dy + dz * dz;
    }

    float toutA = 0.f, toutB = 0.f;

    if (__ballot(nn < 0.0101f)) {                 // ~23% of waves
        for (int k = 0; k < K_PTS; ++k) {
            float w = 0.f;
            if (nn < 0.0101f) {
                float dot = dx * s_kx[k] + dy * s_ky[k] + dz * s_kz[k];
                float sq  = fmaxf(nn - 2.f * dot + s_kk[k], 0.f);  // ref expansion
                if (sq < 0.0025f)                  // sqrt(sq) < 0.05 => w > 0
                    w = 1.f - sqrtf(sq) * 20.f;    // 1/0.05 == 20 exactly
            }
            const unsigned long long em = __ballot(w > 0.f);
            if (!em) continue;                     // common: k has no hits

            const float* wk = weight + (size_t)k * CIN * COUT;

            unsigned emA = (unsigned)(em & 0xffffffffull);   // point A events
            while (emA) {
                float racc = 0.f;
                do {
                    const int src = __builtin_ctz(emA); emA &= emA - 1;
                    const float wsrc = __shfl(w,   src);
                    const int   isrc = __shfl(idx, src);
                    racc = fmaf(wsrc, x[(size_t)isrc * CIN + lane], racc);
                } while (emA);
                s_bc[wv][lane] = racc;
                asm volatile("" ::: "memory");
                float p0 = 0.f, p1 = 0.f, p2 = 0.f, p3 = 0.f;
                #pragma unroll 8
                for (int c = 0; c < CIN; c += 4) {
                    p0 = fmaf(s_bc[wv][c + 0], wk[(c + 0) * COUT + lane], p0);
                    p1 = fmaf(s_bc[wv][c + 1], wk[(c + 1) * COUT + lane], p1);
                    p2 = fmaf(s_bc[wv][c + 2], wk[(c + 2) * COUT + lane], p2);
                    p3 = fmaf(s_bc[wv][c + 3], wk[(c + 3) * COUT + lane], p3);
                }
                toutA += (p0 + p1) + (p2 + p3);
                asm volatile("" ::: "memory");
            }

            unsigned emB = (unsigned)(em >> 32);             // point B events
            while (emB) {
                float racc = 0.f;
                do {
                    const int src = 32 + __builtin_ctz(emB); emB &= emB - 1;
                    const float wsrc = __shfl(w,   src);
                    const int   isrc = __shfl(idx, src);
                    racc = fmaf(wsrc, x[(size_t)isrc * CIN + lane], racc);
                } while (emB);
                s_bc[wv][lane] = racc;
                asm volatile("" ::: "memory");
                float p0 = 0.f, p1 = 0.f, p2 = 0.f, p3 = 0.f;
                #pragma unroll 8
                for (int c = 0; c < CIN; c += 4) {
                    p0 = fmaf(s_bc[wv][c + 0], wk[(c + 0) * COUT + lane], p0);
                    p1 = fmaf(s_bc[wv][c + 1], wk[(c + 1) * COUT + lane], p1);
                    p2 = fmaf(s_bc[wv][c + 2], wk[(c + 2) * COUT + lane], p2);
                    p3 = fmaf(s_bc[wv][c + 3], wk[(c + 3) * COUT + lane], p3);
                }
                toutB += (p0 + p1) + (p2 + p3);
                asm volatile("" ::: "memory");
            }
        }
    }

    out[(size_t)(base + 0) * COUT + lane] = toutA;  // wave owns both rows
    out[(size_t)(base + 1) * COUT + lane] = toutB;
}

extern "C" void kernel_launch(void* const* d_in, const int* in_sizes, int n_in,
                              void* d_out, int out_size, void* d_ws, size_t ws_size,
                              hipStream_t stream) {
    const float* query     = (const float*)d_in[0];
    const float* support   = (const float*)d_in[1];
    const int*   neighbors = (const int*)  d_in[2];
    const float* x         = (const float*)d_in[3];
    const float* kpts      = (const float*)d_in[4];
    const float* weight    = (const float*)d_in[5];
    float*       out       = (float*)d_out;

    kpconv_fused2<<<N_Q / 4, 128, 0, stream>>>(     // 12500 blocks, 2 waves each
        query, support, neighbors, x, kpts, weight, out);
}